// Round 6
// baseline (2415.957 us; speedup 1.0000x reference)
//
#include <hip/hip_runtime.h>
#include <hip/hip_bf16.h>

// ---------------------------------------------------------------------------
// LSTM (faithful-bug variant) on MI355X — fused per-step kernel, v4.
// carry (a, b):  a = cell chain, b = hidden chain (fed into the matmul)
//   z[g] = b_prev @ Wc[g]^T + T[x_t][g]     (T = embed-part + bias, per token)
//   g=tanh(z0) i=sig(z1) f=sig(z2) o=sig(z3)
//   a_new = g*i + a_prev*f ;  b_new = tanh(a_new)*o
// output = softmax(a_final @ w_p^T + b_p)
//
// Swapped GEMM Zt[wcol][batch] = Wt[wcol][k] · h_prev[batch][k], wcol = j*4+g.
// v4: 32x32x16 MFMA (halves LDS-read bytes/FLOP vs 16x16x32), block 128 wcol
// x 128 batch, 8 waves = 4 sub-tile pairs x 2 K-halves (K-split), grid 256.
// Pair members exchange partial acc via one swizzled LDS round; epilogue is
// split between the pair. Counted-vmcnt double-buffered staging, XOR swizzle.
// C/D layout 32x32 (m74/m101): col=l&31, row=(reg&3)+8*(reg>>2)+4*(l>>5)
//  -> with wcol=j*4+g interleave, reg = jj*4+g: 4 gate-quads per fragment.
// ---------------------------------------------------------------------------

typedef __attribute__((ext_vector_type(8))) short bf16x8;
typedef __attribute__((ext_vector_type(4))) float f32x4;
typedef __attribute__((ext_vector_type(16))) float f32x16;

#define GLOBAL_AS __attribute__((address_space(1)))
#define LDS_AS    __attribute__((address_space(3)))

static __device__ __forceinline__ void async_copy16(const void* g, void* l) {
    __builtin_amdgcn_global_load_lds((const GLOBAL_AS void*)g, (LDS_AS void*)l, 16, 0, 0);
}
static __device__ __forceinline__ float sigm(float x) {
    return 1.f / (1.f + __expf(-x));
}
static __device__ __forceinline__ float tanh_fast(float x) {
    return 1.f - 2.f / (__expf(2.f * x) + 1.f);
}

// ---------------- prep 1: gate table T[s][j*4+g] (embed part + bias) -------
__global__ __launch_bounds__(256) void prep_table(
    const float* __restrict__ embed,                       // [128][256]
    const float* __restrict__ wg, const float* __restrict__ wi,
    const float* __restrict__ wf, const float* __restrict__ wo,
    const float* __restrict__ bg, const float* __restrict__ bi,
    const float* __restrict__ bff, const float* __restrict__ bo,
    float* __restrict__ T)                                 // [128][4096] interleaved
{
    __shared__ float e[8][256];
    const int tid = threadIdx.x;
    const int col = blockIdx.x * 256 + tid;                // 0..4095
    const int s0 = blockIdx.y * 8;
    const int j = col >> 2, g = col & 3;
    const float* w = (g == 0 ? wg : g == 1 ? wi : g == 2 ? wf : wo) + (size_t)j * 1280;
    const float bias = (g == 0 ? bg : g == 1 ? bi : g == 2 ? bff : bo)[j];
    #pragma unroll
    for (int i = 0; i < 8; ++i) e[i][tid] = embed[(s0 + i) * 256 + tid];
    __syncthreads();
    const float4* w4 = (const float4*)w;
    float acc[8];
    #pragma unroll
    for (int i = 0; i < 8; ++i) acc[i] = bias;
    for (int d = 0; d < 64; ++d) {
        const float4 wv = w4[d];
        #pragma unroll
        for (int i = 0; i < 8; ++i) {
            const float4 ev = ((const float4*)e[i])[d];
            acc[i] += ev.x * wv.x + ev.y * wv.y + ev.z * wv.z + ev.w * wv.w;
        }
    }
    #pragma unroll
    for (int i = 0; i < 8; ++i)
        T[(size_t)(s0 + i) * 4096 + col] = acc[i];
}

// ---------------- prep 2: pack recurrent weights bf16, gate-interleaved ----
__global__ __launch_bounds__(256) void pack_w(
    const float* __restrict__ wg, const float* __restrict__ wi,
    const float* __restrict__ wf, const float* __restrict__ wo,
    __hip_bfloat16* __restrict__ Wt)                       // [4096][1024]
{
    const int col = blockIdx.x;                            // wcol = j*4+g
    const int j = col >> 2, g = col & 3;
    const float* w = (g == 0 ? wg : g == 1 ? wi : g == 2 ? wf : wo)
                     + (size_t)j * 1280 + 256;             // skip embed part
    __hip_bfloat16* out = Wt + (size_t)col * 1024;
    for (int k = threadIdx.x; k < 1024; k += 256)
        out[k] = __float2bfloat16(w[k]);
}

// ---------------- fused LSTM step ------------------------------------------
// grid 256 (32 wcb x 8 bb), 512 threads = 8 waves = pair p(0..3) x khalf h.
// Sub-tile p: (pm,pn) 64x64 within the 128x128 block tile; wave computes
// K in [h*512, h*512+512) with acc[2][2] of 32x32x16; pair exchanges via LDS.
// LDS/buffer: {W kh0|W kh1|H kh0|H kh1} x 16KB = 64KB; double-buffered 128KB.
__global__ __launch_bounds__(512, 2) void step_fused(
    const __hip_bfloat16* __restrict__ Wt,   // [4096][1024]
    const float* __restrict__ T,             // [128][4096] interleaved
    const int* __restrict__ X,               // [1024][128]
    const __hip_bfloat16* __restrict__ Hprev,// [1024][1024]
    __hip_bfloat16* __restrict__ Hnext,      // [1024][1024]
    float* __restrict__ CSblob,              // [256*512*8] per-thread cell state
    float* __restrict__ CSout,               // [1024][1024], written at t==127
    int t)
{
    __shared__ char lds[2][65536];
    const int tid = threadIdx.x;
    const int w = tid >> 6, l = tid & 63;
    const int h = w & 1;                     // K-half
    const int p = w >> 1;                    // sub-tile pair 0..3
    const int pm = p >> 1, pn = p & 1;
    const int wcol0 = (blockIdx.x & 31) * 128;
    const int batch0 = (blockIdx.x >> 5) * 128;
    const int hi = l >> 5, lr = l & 31;

    // slot s: row=s>>3, chunk=s&7 (16B chunks of a 128B row of [128][64] bf16)
    // LDS dest linear in s; global SOURCE chunk is ch^(row&7); reader applies
    // the same XOR -> involution cancels (rule 21).
#define STAGE(BUF, KT) do {                                                  \
        _Pragma("unroll")                                                    \
        for (int tau = 0; tau < 4; ++tau) {                                  \
            _Pragma("unroll")                                                \
            for (int i_ = 0; i_ < 2; ++i_) {                                 \
                const int s_ = tid + i_ * 512;                               \
                const int r_ = s_ >> 3, c_ = s_ & 7;                         \
                const int kq_ = (tau & 1) * 512 + (KT) * 64                  \
                                + ((c_ ^ (r_ & 7)) << 3);                    \
                const __hip_bfloat16* src_ = (tau < 2)                       \
                    ? Wt + (size_t)(wcol0 + r_) * 1024 + kq_                 \
                    : Hprev + (size_t)(batch0 + r_) * 1024 + kq_;            \
                async_copy16(src_, &lds[BUF][tau * 16384 + s_ * 16]);        \
            }                                                                \
        }                                                                    \
    } while (0)

    // ---- epilogue inputs (issued before staging; drained by prologue wait)
    int batchN[2];
    #pragma unroll
    for (int n = 0; n < 2; ++n) batchN[n] = batch0 + pn * 64 + n * 32 + lr;
    int sN[2];
    #pragma unroll
    for (int n = 0; n < 2; ++n) sN[n] = X[batchN[n] * 128 + t];

    float* blob = CSblob + ((size_t)blockIdx.x * 512 + tid) * 8;
    float ap[8];
    if (t > 0) {
        f32x4 b0 = *(const f32x4*)&blob[0];
        f32x4 b1 = *(const f32x4*)&blob[4];
        #pragma unroll
        for (int c = 0; c < 4; ++c) { ap[c] = b0[c]; ap[4 + c] = b1[c]; }
    } else {
        #pragma unroll
        for (int c = 0; c < 8; ++c) ap[c] = 0.f;
    }

    // ---- prologue: K-tile 0 ------------------------------------------------
    STAGE(0, 0);
    asm volatile("s_waitcnt vmcnt(0)" ::: "memory");
    __builtin_amdgcn_s_barrier();

    f32x16 acc[2][2];                        // [m-slot][n]; m-slot 0 -> m=h
    #pragma unroll
    for (int i = 0; i < 2; ++i)
        #pragma unroll
        for (int n = 0; n < 2; ++n)
            #pragma unroll
            for (int c = 0; c < 16; ++c) acc[i][n][c] = 0.f;

    // ---- K loop: 8 tiles of BK=64 per K-half, counted vmcnt ---------------
    #pragma unroll
    for (int kt = 0; kt < 8; ++kt) {
        if (kt < 7) STAGE((kt + 1) & 1, kt + 1);
        if (kt > 0) {
            if (kt == 7) asm volatile("s_waitcnt vmcnt(0)" ::: "memory");
            else         asm volatile("s_waitcnt vmcnt(8)" ::: "memory");
            __builtin_amdgcn_s_barrier();    // tile kt ready in LDS
        }
        const char* wb = &lds[kt & 1][h * 16384];
        const char* hb = &lds[kt & 1][32768 + h * 16384];
        #pragma unroll
        for (int kk = 0; kk < 4; ++kk) {
            bf16x8 af[2], bfr[2];
            #pragma unroll
            for (int i = 0; i < 2; ++i) {    // m-slot i -> global m = h^i
                const int row = pm * 64 + ((h ^ i) << 5) + lr;
                const int ch = (kk * 2 + hi) ^ (row & 7);
                af[i] = *(const bf16x8*)(wb + (row * 8 + ch) * 16);
            }
            #pragma unroll
            for (int n = 0; n < 2; ++n) {
                const int row = pn * 64 + (n << 5) + lr;
                const int ch = (kk * 2 + hi) ^ (row & 7);
                bfr[n] = *(const bf16x8*)(hb + (row * 8 + ch) * 16);
            }
            #pragma unroll
            for (int i = 0; i < 2; ++i)
                #pragma unroll
                for (int n = 0; n < 2; ++n)
                    acc[i][n] = __builtin_amdgcn_mfma_f32_32x32x16_bf16(
                        af[i], bfr[n], acc[i][n], 0, 0, 0);
        }
        if (kt < 7) __builtin_amdgcn_s_barrier();  // reads of this buf done
    }
#undef STAGE

    // ---- pair exchange: write m-slot 1 (global m = 1-h), read global m = h.
    // Swizzled 16B slots: float idx = p*4096 + (l*16 + (u ^ (l&15)))*4 ->
    // conflict-free b128 across each 8-lane group.
    float* red = (float*)&lds[0][0];         // reuse buf0 (64KB = 4 pairs x 16KB)
    #pragma unroll
    for (int n = 0; n < 2; ++n)
        #pragma unroll
        for (int q = 0; q < 4; ++q) {
            const int u = ((1 - h) * 2 + n) * 4 + q;
            f32x4 v = { acc[1][n][q * 4 + 0], acc[1][n][q * 4 + 1],
                        acc[1][n][q * 4 + 2], acc[1][n][q * 4 + 3] };
            *(f32x4*)&red[p * 4096 + (l * 16 + (u ^ (l & 15))) * 4] = v;
        }
    __syncthreads();
    #pragma unroll
    for (int n = 0; n < 2; ++n)
        #pragma unroll
        for (int q = 0; q < 4; ++q) {
            const int u = (h * 2 + n) * 4 + q;
            const f32x4 v = *(const f32x4*)&red[p * 4096 + (l * 16 + (u ^ (l & 15))) * 4];
            #pragma unroll
            for (int g = 0; g < 4; ++g) acc[0][n][q * 4 + g] += v[g];
        }

    // ---- in-register epilogue (this wave finalizes global m = h) ----------
    const int jbase = (wcol0 >> 2) + pm * 16 + h * 8;
    f32x4 tvv[2][4];
    #pragma unroll
    for (int n = 0; n < 2; ++n)
        #pragma unroll
        for (int q = 0; q < 4; ++q)
            tvv[n][q] = *(const f32x4*)&T[(size_t)sN[n] * 4096 + (jbase + q * 2 + hi) * 4];

    #pragma unroll
    for (int n = 0; n < 2; ++n)
        #pragma unroll
        for (int q = 0; q < 4; ++q) {
            const int j = jbase + q * 2 + hi;
            const float z0 = acc[0][n][q * 4 + 0] + tvv[n][q][0];
            const float z1 = acc[0][n][q * 4 + 1] + tvv[n][q][1];
            const float z2 = acc[0][n][q * 4 + 2] + tvv[n][q][2];
            const float z3 = acc[0][n][q * 4 + 3] + tvv[n][q][3];
            const float gg = tanh_fast(z0);
            const float ii = sigm(z1);
            const float ff = sigm(z2);
            const float oo = sigm(z3);
            const float na = gg * ii + ap[n * 4 + q] * ff;
            blob[n * 4 + q] = na;
            Hnext[(size_t)batchN[n] * 1024 + j] = __float2bfloat16(tanh_fast(na) * oo);
            if (t == 127)
                CSout[(size_t)batchN[n] * 1024 + j] = na;
        }
}

// ---------------- final projection + softmax -------------------------------
__global__ __launch_bounds__(256) void proj_softmax(
    const float* __restrict__ A,             // [1024][1024]
    const float* __restrict__ Wp,            // [10][1024]
    const float* __restrict__ bp,            // [10]
    float* __restrict__ out)                 // [1024][10]
{
    const int row = blockIdx.x;
    const float* a = A + (size_t)row * 1024;
    float p[10];
    #pragma unroll
    for (int c = 0; c < 10; ++c) p[c] = 0.f;
    for (int k = threadIdx.x; k < 1024; k += 256) {
        const float av = a[k];
        #pragma unroll
        for (int c = 0; c < 10; ++c) p[c] += av * Wp[c * 1024 + k];
    }
    #pragma unroll
    for (int c = 0; c < 10; ++c)
        #pragma unroll
        for (int off = 32; off; off >>= 1) p[c] += __shfl_down(p[c], off);
    __shared__ float red[4][10];
    const int wv = threadIdx.x >> 6, ln = threadIdx.x & 63;
    if (ln == 0)
        for (int c = 0; c < 10; ++c) red[wv][c] = p[c];
    __syncthreads();
    if (threadIdx.x == 0) {
        float logits[10], mx = -1e30f;
        for (int c = 0; c < 10; ++c) {
            logits[c] = red[0][c] + red[1][c] + red[2][c] + red[3][c] + bp[c];
            mx = fmaxf(mx, logits[c]);
        }
        float sum = 0.f;
        for (int c = 0; c < 10; ++c) { logits[c] = __expf(logits[c] - mx); sum += logits[c]; }
        const float inv = 1.f / sum;
        for (int c = 0; c < 10; ++c) out[(size_t)row * 10 + c] = logits[c] * inv;
    }
}

// ---------------------------------------------------------------------------
extern "C" void kernel_launch(void* const* d_in, const int* in_sizes, int n_in,
                              void* d_out, int out_size, void* d_ws, size_t ws_size,
                              hipStream_t stream) {
    (void)in_sizes; (void)n_in; (void)out_size; (void)ws_size;
    const int*   x     = (const int*)d_in[0];
    const float* embed = (const float*)d_in[1];
    const float* wg    = (const float*)d_in[2];
    const float* wi    = (const float*)d_in[3];
    const float* wf    = (const float*)d_in[4];
    const float* wo    = (const float*)d_in[5];
    const float* bg    = (const float*)d_in[6];
    const float* bi    = (const float*)d_in[7];
    const float* bff   = (const float*)d_in[8];
    const float* bo    = (const float*)d_in[9];
    const float* wp    = (const float*)d_in[10];
    const float* bp    = (const float*)d_in[11];
    float* out = (float*)d_out;

    char* ws = (char*)d_ws;
    float*          T    = (float*)(ws);                        // 2 MB
    __hip_bfloat16* Wt   = (__hip_bfloat16*)(ws + (2u << 20));  // 8 MB
    __hip_bfloat16* BhA  = (__hip_bfloat16*)(ws + (10u << 20)); // 2 MB
    __hip_bfloat16* BhB  = (__hip_bfloat16*)(ws + (12u << 20)); // 2 MB
    float*          CSo  = (float*)(ws + (14u << 20));          // 4 MB
    float*          CSb  = (float*)(ws + (18u << 20));          // 4 MB

    prep_table<<<dim3(16, 16), 256, 0, stream>>>(embed, wg, wi, wf, wo, bg, bi, bff, bo, T);
    pack_w<<<4096, 256, 0, stream>>>(wg, wi, wf, wo, Wt);
    hipMemsetAsync(BhA, 0, (size_t)1024 * 1024 * sizeof(__hip_bfloat16), stream);

    for (int t = 0; t < 128; ++t) {
        const __hip_bfloat16* Hp = (t & 1) ? BhB : BhA;
        __hip_bfloat16*       Hn = (t & 1) ? BhA : BhB;
        step_fused<<<256, 512, 0, stream>>>(Wt, T, x, Hp, Hn, CSb, CSo, t);
    }
    proj_softmax<<<1024, 256, 0, stream>>>(CSo, wp, bp, out);
}

// Round 7
// 2157.963 us; speedup vs baseline: 1.1196x; 1.1196x over previous
//
#include <hip/hip_runtime.h>
#include <hip/hip_bf16.h>

// ---------------------------------------------------------------------------
// LSTM (faithful-bug variant) on MI355X — fused per-step kernel, v5.
// carry (a, b):  a = cell chain, b = hidden chain (fed into the matmul)
//   z[g] = b_prev @ Wc[g]^T + T[x_t][g]     (T = embed-part + bias, per token)
//   g=tanh(z0) i=sig(z1) f=sig(z2) o=sig(z3)
//   a_new = g*i + a_prev*f ;  b_new = tanh(a_new)*o
// output = softmax(a_final @ w_p^T + b_p)
//
// Swapped GEMM Zt[wcol][batch] = Wt[wcol][k] · h_prev[batch][k], wcol = j*4+g
// so each lane's 4 acc regs are the 4 gates of one (batch, j) pair.
// v5 (vs v2/R4): TRIPLE-buffered LDS with 2-tiles-ahead prefetch (vmcnt waits
// for loads issued 2 iterations ago) and ONE barrier per K-tile (3-buffer
// distance makes the read-done barrier redundant), setprio around MFMAs.
// Tile 128 wcol x 64 batch, BK=64, grid 512 (2 blocks/CU), XOR-swizzled LDS.
// ---------------------------------------------------------------------------

typedef __attribute__((ext_vector_type(8))) short bf16x8;
typedef __attribute__((ext_vector_type(4))) float f32x4;

#define GLOBAL_AS __attribute__((address_space(1)))
#define LDS_AS    __attribute__((address_space(3)))

static __device__ __forceinline__ void async_copy16(const void* g, void* l) {
    __builtin_amdgcn_global_load_lds((const GLOBAL_AS void*)g, (LDS_AS void*)l, 16, 0, 0);
}
static __device__ __forceinline__ float sigm(float x) {
    return 1.f / (1.f + __expf(-x));
}
static __device__ __forceinline__ float tanh_fast(float x) {
    return 1.f - 2.f / (__expf(2.f * x) + 1.f);
}

// ---------------- prep 1: gate table T[s][j*4+g] (embed part + bias) -------
// grid (16 colblocks, 16 s-blocks) x 256 threads; 8 s-rows per block.
__global__ __launch_bounds__(256) void prep_table(
    const float* __restrict__ embed,                       // [128][256]
    const float* __restrict__ wg, const float* __restrict__ wi,
    const float* __restrict__ wf, const float* __restrict__ wo,
    const float* __restrict__ bg, const float* __restrict__ bi,
    const float* __restrict__ bff, const float* __restrict__ bo,
    float* __restrict__ T)                                 // [128][4096] interleaved
{
    __shared__ float e[8][256];
    const int tid = threadIdx.x;
    const int col = blockIdx.x * 256 + tid;                // 0..4095
    const int s0 = blockIdx.y * 8;
    const int j = col >> 2, g = col & 3;
    const float* w = (g == 0 ? wg : g == 1 ? wi : g == 2 ? wf : wo) + (size_t)j * 1280;
    const float bias = (g == 0 ? bg : g == 1 ? bi : g == 2 ? bff : bo)[j];
    #pragma unroll
    for (int i = 0; i < 8; ++i) e[i][tid] = embed[(s0 + i) * 256 + tid];
    __syncthreads();
    const float4* w4 = (const float4*)w;
    float acc[8];
    #pragma unroll
    for (int i = 0; i < 8; ++i) acc[i] = bias;
    for (int d = 0; d < 64; ++d) {
        const float4 wv = w4[d];
        #pragma unroll
        for (int i = 0; i < 8; ++i) {
            const float4 ev = ((const float4*)e[i])[d];
            acc[i] += ev.x * wv.x + ev.y * wv.y + ev.z * wv.z + ev.w * wv.w;
        }
    }
    #pragma unroll
    for (int i = 0; i < 8; ++i)
        T[(size_t)(s0 + i) * 4096 + col] = acc[i];
}

// ---------------- prep 2: pack recurrent weights bf16, gate-interleaved ----
__global__ __launch_bounds__(256) void pack_w(
    const float* __restrict__ wg, const float* __restrict__ wi,
    const float* __restrict__ wf, const float* __restrict__ wo,
    __hip_bfloat16* __restrict__ Wt)                       // [4096][1024]
{
    const int col = blockIdx.x;                            // wcol = j*4+g
    const int j = col >> 2, g = col & 3;
    const float* w = (g == 0 ? wg : g == 1 ? wi : g == 2 ? wf : wo)
                     + (size_t)j * 1280 + 256;             // skip embed part
    __hip_bfloat16* out = Wt + (size_t)col * 1024;
    for (int k = threadIdx.x; k < 1024; k += 256)
        out[k] = __float2bfloat16(w[k]);
}

// ---------------- fused LSTM step ------------------------------------------
// grid 512: wcb = bid&31 (128 wcols), bb = bid>>5 (64 batch). 512 threads,
// 8 waves in 4(wm) x 2(wn); wave tile 32 wcol x 32 batch, acc[2][2].
// LDS: 3 buffers x { Ws 128x64 bf16 16KB | Hs 64x64 8KB } = 72KB.
// Pipeline: stage kt+2 after barrier kt; vmcnt(3) waits for the stage issued
// two iterations earlier (2 stages x 3 loads in flight).
__global__ __launch_bounds__(512, 4) void step_fused(
    const __hip_bfloat16* __restrict__ Wt,   // [4096][1024]
    const float* __restrict__ T,             // [128][4096] interleaved
    const int* __restrict__ X,               // [1024][128]
    const __hip_bfloat16* __restrict__ Hprev,// [1024][1024]
    __hip_bfloat16* __restrict__ Hnext,      // [1024][1024]
    float* __restrict__ CSblob,              // [512*512*4] per-thread cell state
    float* __restrict__ CSout,               // [1024][1024], written at t==127
    int t)
{
    __shared__ char lds[3][24576];           // [buf]{ Ws 16KB | Hs 8KB }
    const int tid = threadIdx.x;
    const int w = tid >> 6, l = tid & 63;
    const int wm = w >> 1, wn = w & 1;
    const int wcol0 = (blockIdx.x & 31) * 128;
    const int batch0 = (blockIdx.x >> 5) * 64;

    // slot s: row = s>>3, chunk = s&7 (16B chunks of the 128B row).
    // LDS dest linear in s; global SOURCE chunk is ch^(row&7); reader applies
    // the same XOR -> involution cancels (rule 21).
#define STAGE(K0, BUF) do {                                                    \
        _Pragma("unroll")                                                      \
        for (int i_ = 0; i_ < 2; ++i_) {                                       \
            const int sW = tid + i_ * 512;                                     \
            const int rW = sW >> 3, cW = sW & 7;                               \
            async_copy16(Wt + (size_t)(wcol0 + rW) * 1024 + (K0)               \
                             + ((cW ^ (rW & 7)) << 3),                         \
                         &lds[BUF][sW * 16]);                                  \
        }                                                                      \
        const int sH = tid;                                                    \
        const int rH = sH >> 3, cH = sH & 7;                                   \
        async_copy16(Hprev + (size_t)(batch0 + rH) * 1024 + (K0)               \
                         + ((cH ^ (rH & 7)) << 3),                             \
                     &lds[BUF][16384 + sH * 16]);                              \
    } while (0)

    // ---- issue the first two stages IMMEDIATELY (latency head start) ------
    STAGE(0, 0);
    STAGE(64, 1);

    // ---- epilogue inputs (drained as a side effect of iter-0/1 vmcnt) -----
    int batchN[2], jM[2];
    #pragma unroll
    for (int n = 0; n < 2; ++n) batchN[n] = batch0 + wn * 32 + n * 16 + (l & 15);
    #pragma unroll
    for (int m = 0; m < 2; ++m) jM[m] = (wcol0 >> 2) + wm * 8 + m * 4 + (l >> 4);

    f32x4 tv[2][2];
    float ap[2][2];
    #pragma unroll
    for (int n = 0; n < 2; ++n) {
        const int s = X[batchN[n] * 128 + t];
        #pragma unroll
        for (int m = 0; m < 2; ++m)
            tv[m][n] = *(const f32x4*)&T[(size_t)s * 4096 + jM[m] * 4];
    }
    float* blob = CSblob + ((size_t)blockIdx.x * 512 + tid) * 4;
    if (t > 0) {
        #pragma unroll
        for (int m = 0; m < 2; ++m)
            #pragma unroll
            for (int n = 0; n < 2; ++n) ap[m][n] = blob[m * 2 + n];
    } else {
        #pragma unroll
        for (int m = 0; m < 2; ++m)
            #pragma unroll
            for (int n = 0; n < 2; ++n) ap[m][n] = 0.f;
    }

    f32x4 acc[2][2];
    const f32x4 z4 = {0.f, 0.f, 0.f, 0.f};
    #pragma unroll
    for (int m = 0; m < 2; ++m)
        #pragma unroll
        for (int n = 0; n < 2; ++n) acc[m][n] = z4;

    // ---- K loop: 16 tiles of BK=64, 3-buffer, 2-ahead, 1 barrier/tile -----
    // vmcnt(3): waits for the 3-load stage issued two iterations ago; the
    // epilogue-input loads above are older still, so they drain first and the
    // count remains correct. (kt=15: full drain.)
    #pragma unroll
    for (int kt = 0; kt < 16; ++kt) {
        if (kt == 15) asm volatile("s_waitcnt vmcnt(0)" ::: "memory");
        else          asm volatile("s_waitcnt vmcnt(3)" ::: "memory");
        __builtin_amdgcn_s_barrier();        // tile kt in LDS for ALL waves;
                                             // also: compute(kt-1) done ->
                                             // safe to overwrite buf[(kt+2)%3]
        if (kt < 14) STAGE((kt + 2) * 64, (kt + 2) % 3);

        const char* base = &lds[kt % 3][0];
        bf16x8 af0[2], bfr0[2], af1[2], bfr1[2];
        #pragma unroll
        for (int m = 0; m < 2; ++m) {
            const int row = wm * 32 + m * 16 + (l & 15);
            const int ch0 = (l >> 4) ^ (row & 7);
            const int ch1 = (4 + (l >> 4)) ^ (row & 7);
            af0[m] = *(const bf16x8*)(base + (row * 8 + ch0) * 16);
            af1[m] = *(const bf16x8*)(base + (row * 8 + ch1) * 16);
        }
        #pragma unroll
        for (int n = 0; n < 2; ++n) {
            const int row = wn * 32 + n * 16 + (l & 15);
            const int ch0 = (l >> 4) ^ (row & 7);
            const int ch1 = (4 + (l >> 4)) ^ (row & 7);
            bfr0[n] = *(const bf16x8*)(base + 16384 + (row * 8 + ch0) * 16);
            bfr1[n] = *(const bf16x8*)(base + 16384 + (row * 8 + ch1) * 16);
        }
        __builtin_amdgcn_s_setprio(1);
        #pragma unroll
        for (int m = 0; m < 2; ++m)
            #pragma unroll
            for (int n = 0; n < 2; ++n)
                acc[m][n] = __builtin_amdgcn_mfma_f32_16x16x32_bf16(
                    af0[m], bfr0[n], acc[m][n], 0, 0, 0);
        #pragma unroll
        for (int m = 0; m < 2; ++m)
            #pragma unroll
            for (int n = 0; n < 2; ++n)
                acc[m][n] = __builtin_amdgcn_mfma_f32_16x16x32_bf16(
                    af1[m], bfr1[n], acc[m][n], 0, 0, 0);
        __builtin_amdgcn_s_setprio(0);
    }
#undef STAGE

    // ---- in-register epilogue --------------------------------------------
    #pragma unroll
    for (int m = 0; m < 2; ++m)
        #pragma unroll
        for (int n = 0; n < 2; ++n) {
            const float z0 = acc[m][n][0] + tv[m][n][0];
            const float z1 = acc[m][n][1] + tv[m][n][1];
            const float z2 = acc[m][n][2] + tv[m][n][2];
            const float z3 = acc[m][n][3] + tv[m][n][3];
            const float gg = tanh_fast(z0);
            const float ii = sigm(z1);
            const float ff = sigm(z2);
            const float oo = sigm(z3);
            const float na = gg * ii + ap[m][n] * ff;
            blob[m * 2 + n] = na;
            Hnext[(size_t)batchN[n] * 1024 + jM[m]] =
                __float2bfloat16(tanh_fast(na) * oo);
            if (t == 127)
                CSout[(size_t)batchN[n] * 1024 + jM[m]] = na;
        }
}

// ---------------- final projection + softmax -------------------------------
__global__ __launch_bounds__(256) void proj_softmax(
    const float* __restrict__ A,             // [1024][1024]
    const float* __restrict__ Wp,            // [10][1024]
    const float* __restrict__ bp,            // [10]
    float* __restrict__ out)                 // [1024][10]
{
    const int row = blockIdx.x;
    const float* a = A + (size_t)row * 1024;
    float p[10];
    #pragma unroll
    for (int c = 0; c < 10; ++c) p[c] = 0.f;
    for (int k = threadIdx.x; k < 1024; k += 256) {
        const float av = a[k];
        #pragma unroll
        for (int c = 0; c < 10; ++c) p[c] += av * Wp[c * 1024 + k];
    }
    #pragma unroll
    for (int c = 0; c < 10; ++c)
        #pragma unroll
        for (int off = 32; off; off >>= 1) p[c] += __shfl_down(p[c], off);
    __shared__ float red[4][10];
    const int wv = threadIdx.x >> 6, ln = threadIdx.x & 63;
    if (ln == 0)
        for (int c = 0; c < 10; ++c) red[wv][c] = p[c];
    __syncthreads();
    if (threadIdx.x == 0) {
        float logits[10], mx = -1e30f;
        for (int c = 0; c < 10; ++c) {
            logits[c] = red[0][c] + red[1][c] + red[2][c] + red[3][c] + bp[c];
            mx = fmaxf(mx, logits[c]);
        }
        float sum = 0.f;
        for (int c = 0; c < 10; ++c) { logits[c] = __expf(logits[c] - mx); sum += logits[c]; }
        const float inv = 1.f / sum;
        for (int c = 0; c < 10; ++c) out[(size_t)row * 10 + c] = logits[c] * inv;
    }
}

// ---------------------------------------------------------------------------
extern "C" void kernel_launch(void* const* d_in, const int* in_sizes, int n_in,
                              void* d_out, int out_size, void* d_ws, size_t ws_size,
                              hipStream_t stream) {
    (void)in_sizes; (void)n_in; (void)out_size; (void)ws_size;
    const int*   x     = (const int*)d_in[0];
    const float* embed = (const float*)d_in[1];
    const float* wg    = (const float*)d_in[2];
    const float* wi    = (const float*)d_in[3];
    const float* wf    = (const float*)d_in[4];
    const float* wo    = (const float*)d_in[5];
    const float* bg    = (const float*)d_in[6];
    const float* bi    = (const float*)d_in[7];
    const float* bff   = (const float*)d_in[8];
    const float* bo    = (const float*)d_in[9];
    const float* wp    = (const float*)d_in[10];
    const float* bp    = (const float*)d_in[11];
    float* out = (float*)d_out;

    char* ws = (char*)d_ws;
    float*          T    = (float*)(ws);                        // 2 MB
    __hip_bfloat16* Wt   = (__hip_bfloat16*)(ws + (2u << 20));  // 8 MB
    __hip_bfloat16* BhA  = (__hip_bfloat16*)(ws + (10u << 20)); // 2 MB
    __hip_bfloat16* BhB  = (__hip_bfloat16*)(ws + (12u << 20)); // 2 MB
    float*          CSo  = (float*)(ws + (14u << 20));          // 4 MB
    float*          CSb  = (float*)(ws + (18u << 20));          // 4 MB

    prep_table<<<dim3(16, 16), 256, 0, stream>>>(embed, wg, wi, wf, wo, bg, bi, bff, bo, T);
    pack_w<<<4096, 256, 0, stream>>>(wg, wi, wf, wo, Wt);
    hipMemsetAsync(BhA, 0, (size_t)1024 * 1024 * sizeof(__hip_bfloat16), stream);

    for (int t = 0; t < 128; ++t) {
        const __hip_bfloat16* Hp = (t & 1) ? BhB : BhA;
        __hip_bfloat16*       Hn = (t & 1) ? BhA : BhB;
        step_fused<<<512, 512, 0, stream>>>(Wt, T, x, Hp, Hn, CSb, CSo, t);
    }
    proj_softmax<<<1024, 256, 0, stream>>>(CSo, wp, bp, out);
}